// Round 3
// baseline (1023.896 us; speedup 1.0000x reference)
//
#include <hip/hip_runtime.h>
#include <hip/hip_bf16.h>
#include <cstdint>

// ---------------------------------------------------------------------------
// GCN: 3 layers of  h = relu( Ahat * (h @ W) + b ), then log_softmax(h).
// Ahat = D^-1/2 (A + I) D^-1/2 built from edge_index.
// NOTE: harness delivers integer inputs as int32 (NOT int64 as in the
// reference) — cast edge_index to const int*.
// CSR by dst built once per launch (counting sort, int atomics); per layer:
// fp32 LDS-tiled GEMM + per-node gather aggregation (no float atomics).
// d_out doubles as the ping buffer to keep workspace ~59 MB.
// ---------------------------------------------------------------------------

#define D 128           // feature dim (D_IN == D_HID == 128)

// ---------------- CSR build kernels ----------------

__global__ void zero_ints(int* __restrict__ a, int n) {
    int i = blockIdx.x * 256 + threadIdx.x;
    if (i < n) a[i] = 0;
}

__global__ void count_deg(const int* __restrict__ ei, int* __restrict__ cnt, int E) {
    int e = blockIdx.x * 256 + threadIdx.x;
    if (e < E) {
        int d = ei[(size_t)E + e];     // dst row
        atomicAdd(&cnt[d], 1);
    }
}

__global__ void compute_dis(const int* __restrict__ cnt, float* __restrict__ dis, int n) {
    int i = blockIdx.x * 256 + threadIdx.x;
    if (i < n) {
        // self loop always present -> deg >= 1
        dis[i] = rsqrtf((float)(cnt[i] + 1));
    }
}

// block-wise scan (256 elements / block) -> exclusive rowptr + block sums
__global__ void scan_block(const int* __restrict__ cnt, int* __restrict__ rowptr,
                           int* __restrict__ blocksum, int n) {
    __shared__ int s[256];
    int t = threadIdx.x;
    int i = blockIdx.x * 256 + t;
    int v = (i < n) ? cnt[i] : 0;
    s[t] = v;
    __syncthreads();
    for (int off = 1; off < 256; off <<= 1) {
        int u = (t >= off) ? s[t - off] : 0;
        __syncthreads();
        s[t] += u;
        __syncthreads();
    }
    if (i < n) rowptr[i] = s[t] - v;           // exclusive within block
    if (t == 255) blocksum[blockIdx.x] = s[255];
}

// single-block scan of block sums (handles nb > 512 via carried loop)
__global__ void scan_sums(const int* __restrict__ blocksum, int* __restrict__ blockoff, int nb) {
    __shared__ int s[512];
    int t = threadIdx.x;
    int carry = 0;
    for (int base = 0; base < nb; base += 512) {
        int idx = base + t;
        int v = (idx < nb) ? blocksum[idx] : 0;
        s[t] = v;
        __syncthreads();
        for (int off = 1; off < 512; off <<= 1) {
            int u = (t >= off) ? s[t - off] : 0;
            __syncthreads();
            s[t] += u;
            __syncthreads();
        }
        if (idx < nb) blockoff[idx] = carry + s[t] - v;   // exclusive global
        carry += s[511];
        __syncthreads();
    }
}

__global__ void add_offsets(int* __restrict__ rowptr, const int* __restrict__ blockoff,
                            int n, int E) {
    int i = blockIdx.x * 256 + threadIdx.x;
    if (i < n) rowptr[i] += blockoff[i >> 8];
    if (i == 0) rowptr[n] = E;
}

__global__ void fill_csr(const int* __restrict__ ei, const int* __restrict__ rowptr,
                         int* __restrict__ fill, int* __restrict__ col, int E) {
    int e = blockIdx.x * 256 + threadIdx.x;
    if (e < E) {
        int s = ei[e];                 // src row
        int d = ei[(size_t)E + e];     // dst row
        int p = rowptr[d] + atomicAdd(&fill[d], 1);
        col[p] = s;
    }
}

// ---------------- GEMM: Y[n,128] = X[n,128] @ W[128,128] ----------------
// 256 threads, 32 rows per block. W (64KB) + X tile (16KB) = 80KB LDS
// -> 2 blocks/CU. Thread computes 4 rows x 4 cols.
__global__ __launch_bounds__(256, 2)
void gemm128(const float* __restrict__ X, const float* __restrict__ W,
             float* __restrict__ Y, int n) {
    __shared__ float Wl[D * D];      // 64 KB
    __shared__ float Xl[32 * D];     // 16 KB
    int tid = threadIdx.x;
    int row0 = blockIdx.x * 32;

    // stage W (4096 float4)
    {
        const float4* src = (const float4*)W;
        float4* dst = (float4*)Wl;
        for (int i = tid; i < (D * D) / 4; i += 256) dst[i] = src[i];
    }
    // stage X tile (1024 float4), row-major
    for (int i = tid; i < (32 * D) / 4; i += 256) {
        int r = i >> 5;          // row in tile
        int k4 = i & 31;         // float4 index in row
        int row = row0 + r;
        float4 v = make_float4(0.f, 0.f, 0.f, 0.f);
        if (row < n) v = ((const float4*)(X + (size_t)row * D))[k4];
        ((float4*)Xl)[i] = v;
    }
    __syncthreads();

    int c0 = (tid & 31) * 4;
    int r0 = (tid >> 5) * 4;
    float acc[4][4] = {};

#pragma unroll 4
    for (int k = 0; k < D; k++) {
        float4 w = *((const float4*)(Wl + k * D + c0));
        float x0 = Xl[(r0 + 0) * D + k];
        float x1 = Xl[(r0 + 1) * D + k];
        float x2 = Xl[(r0 + 2) * D + k];
        float x3 = Xl[(r0 + 3) * D + k];
        acc[0][0] += x0 * w.x; acc[0][1] += x0 * w.y; acc[0][2] += x0 * w.z; acc[0][3] += x0 * w.w;
        acc[1][0] += x1 * w.x; acc[1][1] += x1 * w.y; acc[1][2] += x1 * w.z; acc[1][3] += x1 * w.w;
        acc[2][0] += x2 * w.x; acc[2][1] += x2 * w.y; acc[2][2] += x2 * w.z; acc[2][3] += x2 * w.w;
        acc[3][0] += x3 * w.x; acc[3][1] += x3 * w.y; acc[3][2] += x3 * w.z; acc[3][3] += x3 * w.w;
    }

#pragma unroll
    for (int r = 0; r < 4; r++) {
        int row = row0 + r0 + r;
        if (row < n) {
            float4 v = make_float4(acc[r][0], acc[r][1], acc[r][2], acc[r][3]);
            *((float4*)(Y + (size_t)row * D + c0)) = v;
        }
    }
}

// ---------------- Aggregation ----------------
// out[i] = act( dis[i] * ( sum_{s in N(i)} dis[s]*H[s] + dis[i]*H[i] ) + b )
// MODE 0: relu.  MODE 1: relu then log_softmax over the 128 features.
// One wave (64 lanes) per node, float2 per lane.
template <int MODE>
__global__ __launch_bounds__(256)
void aggregate(const float* __restrict__ H, const float* __restrict__ dis,
               const int* __restrict__ rowptr, const int* __restrict__ col,
               const float* __restrict__ bias, float* __restrict__ out, int n) {
    int node = blockIdx.x * 4 + (threadIdx.x >> 6);
    if (node >= n) return;
    int lane = threadIdx.x & 63;

    float di = dis[node];
    float2 acc;
    {
        float2 v = ((const float2*)(H + (size_t)node * D))[lane];
        acc.x = di * v.x;
        acc.y = di * v.y;
    }
    int beg = rowptr[node], end = rowptr[node + 1];
    for (int j = beg; j < end; j++) {
        int s = col[j];
        float w = dis[s];
        float2 v = ((const float2*)(H + (size_t)s * D))[lane];
        acc.x += w * v.x;
        acc.y += w * v.y;
    }
    float2 b = ((const float2*)bias)[lane];
    acc.x = di * acc.x + b.x;
    acc.y = di * acc.y + b.y;
    // relu (applied in ALL layers per reference)
    acc.x = fmaxf(acc.x, 0.f);
    acc.y = fmaxf(acc.y, 0.f);

    if (MODE == 1) {
        float m = fmaxf(acc.x, acc.y);
        for (int off = 32; off > 0; off >>= 1) m = fmaxf(m, __shfl_xor(m, off));
        float e = __expf(acc.x - m) + __expf(acc.y - m);
        for (int off = 32; off > 0; off >>= 1) e += __shfl_xor(e, off);
        float ls = m + __logf(e);
        acc.x -= ls;
        acc.y -= ls;
    }
    ((float2*)(out + (size_t)node * D))[lane] = acc;
}

// ---------------- launcher ----------------

static inline size_t align256(size_t x) { return (x + 255) & ~(size_t)255; }

extern "C" void kernel_launch(void* const* d_in, const int* in_sizes, int n_in,
                              void* d_out, int out_size, void* d_ws, size_t ws_size,
                              hipStream_t stream) {
    const float* x  = (const float*)d_in[0];
    const int*   ei = (const int*)d_in[1];      // int32! (harness converts integer inputs)
    const float* W0 = (const float*)d_in[2];
    const float* W1 = (const float*)d_in[3];
    const float* W2 = (const float*)d_in[4];
    const float* b0 = (const float*)d_in[5];
    const float* b1 = (const float*)d_in[6];
    const float* b2 = (const float*)d_in[7];
    float* out      = (float*)d_out;

    const int N = in_sizes[0] / D;
    const int E = in_sizes[1] / 2;

    // workspace bump allocation (~59 MB total)
    char* ws = (char*)d_ws;
    size_t off = 0;
    int*   cnt      = (int*)(ws + off); off = align256(off + (size_t)N * 4);
    int*   fill     = (int*)(ws + off); off = align256(off + (size_t)N * 4);
    float* dis      = (float*)(ws + off); off = align256(off + (size_t)N * 4);
    int*   rowptr   = (int*)(ws + off); off = align256(off + ((size_t)N + 1) * 4);
    int*   blocksum = (int*)(ws + off); off = align256(off + 4096);
    int*   blockoff = (int*)(ws + off); off = align256(off + 4096);
    int*   col      = (int*)(ws + off); off = align256(off + (size_t)E * 4);
    float* bufA     = (float*)(ws + off); off = align256(off + (size_t)N * D * 4);
    (void)ws_size;

    const int nbN = (N + 255) / 256;   // blocks over nodes
    const int nbE = (E + 255) / 256;   // blocks over edges

    // --- CSR build ---
    zero_ints<<<nbN, 256, 0, stream>>>(cnt, N);
    zero_ints<<<nbN, 256, 0, stream>>>(fill, N);
    count_deg<<<nbE, 256, 0, stream>>>(ei, cnt, E);
    compute_dis<<<nbN, 256, 0, stream>>>(cnt, dis, N);
    scan_block<<<nbN, 256, 0, stream>>>(cnt, rowptr, blocksum, N);
    scan_sums<<<1, 512, 0, stream>>>(blocksum, blockoff, nbN);
    add_offsets<<<nbN, 256, 0, stream>>>(rowptr, blockoff, N, E);
    fill_csr<<<nbE, 256, 0, stream>>>(ei, rowptr, fill, col, E);

    const int gemmBlocks = (N + 31) / 32;
    const int aggBlocks  = (N + 3) / 4;

    // --- layer 0: x -> out ---
    gemm128<<<gemmBlocks, 256, 0, stream>>>(x, W0, bufA, N);
    aggregate<0><<<aggBlocks, 256, 0, stream>>>(bufA, dis, rowptr, col, b0, out, N);
    // --- layer 1: out -> out ---
    gemm128<<<gemmBlocks, 256, 0, stream>>>(out, W1, bufA, N);
    aggregate<0><<<aggBlocks, 256, 0, stream>>>(bufA, dis, rowptr, col, b1, out, N);
    // --- layer 2: out -> out (relu + log_softmax) ---
    gemm128<<<gemmBlocks, 256, 0, stream>>>(out, W2, bufA, N);
    aggregate<1><<<aggBlocks, 256, 0, stream>>>(bufA, dis, rowptr, col, b2, out, N);
}

// Round 4
// 853.213 us; speedup vs baseline: 1.2000x; 1.2000x over previous
//
#include <hip/hip_runtime.h>
#include <cstdint>

// ---------------------------------------------------------------------------
// GCN: 3 x [ h = relu( Ahat (h W) + b ) ], then log_softmax.
// Round 4: bf16 activations. Aggregation gathers 256B bf16 rows (half the
// HBM traffic); GEMM uses mfma_f32_16x16x32_bf16 with global A-frag loads and
// L2-resident transposed-W B-frags (no LDS, no barriers).
// edge_index arrives as int32 (harness converts integer inputs).
// ---------------------------------------------------------------------------

#define D 128

typedef __attribute__((ext_vector_type(8))) short bf16x8;
typedef __attribute__((ext_vector_type(4))) float f32x4;

__device__ inline ushort f_to_bf(float f) {
    uint x = __float_as_uint(f);
    return (ushort)((x + 0x7fffu + ((x >> 16) & 1u)) >> 16);   // RNE
}
__device__ inline uint pack_bf2(float a, float b) {
    return (uint)f_to_bf(a) | ((uint)f_to_bf(b) << 16);
}
__device__ inline float bf_lo(uint u) { return __uint_as_float(u << 16); }
__device__ inline float bf_hi(uint u) { return __uint_as_float(u & 0xffff0000u); }

// ---------------- CSR build ----------------

__global__ void zero_ints(int* __restrict__ a, int n) {
    int i = blockIdx.x * 256 + threadIdx.x;
    if (i < n) a[i] = 0;
}

__global__ void count_deg(const int* __restrict__ ei, int* __restrict__ cnt, int E) {
    int e = blockIdx.x * 256 + threadIdx.x;
    if (e < E) atomicAdd(&cnt[ei[(size_t)E + e]], 1);
}

__global__ void compute_dis(const int* __restrict__ cnt, float* __restrict__ dis, int n) {
    int i = blockIdx.x * 256 + threadIdx.x;
    if (i < n) dis[i] = rsqrtf((float)(cnt[i] + 1));   // self loop -> deg >= 1
}

__global__ void scan_block(const int* __restrict__ cnt, int* __restrict__ rowptr,
                           int* __restrict__ blocksum, int n) {
    __shared__ int s[256];
    int t = threadIdx.x;
    int i = blockIdx.x * 256 + t;
    int v = (i < n) ? cnt[i] : 0;
    s[t] = v;
    __syncthreads();
    for (int off = 1; off < 256; off <<= 1) {
        int u = (t >= off) ? s[t - off] : 0;
        __syncthreads();
        s[t] += u;
        __syncthreads();
    }
    if (i < n) rowptr[i] = s[t] - v;
    if (t == 255) blocksum[blockIdx.x] = s[255];
}

__global__ void scan_sums(const int* __restrict__ blocksum, int* __restrict__ blockoff, int nb) {
    __shared__ int s[512];
    int t = threadIdx.x;
    int carry = 0;
    for (int base = 0; base < nb; base += 512) {
        int idx = base + t;
        int v = (idx < nb) ? blocksum[idx] : 0;
        s[t] = v;
        __syncthreads();
        for (int off = 1; off < 512; off <<= 1) {
            int u = (t >= off) ? s[t - off] : 0;
            __syncthreads();
            s[t] += u;
            __syncthreads();
        }
        if (idx < nb) blockoff[idx] = carry + s[t] - v;
        carry += s[511];
        __syncthreads();
    }
}

__global__ void add_offsets(int* __restrict__ rowptr, const int* __restrict__ blockoff,
                            int n, int E) {
    int i = blockIdx.x * 256 + threadIdx.x;
    if (i < n) rowptr[i] += blockoff[i >> 8];
    if (i == 0) rowptr[n] = E;
}

__global__ void fill_csr(const int* __restrict__ ei, const int* __restrict__ rowptr,
                         int* __restrict__ fill, int* __restrict__ col, int E) {
    int e = blockIdx.x * 256 + threadIdx.x;
    if (e < E) {
        int s = ei[e];
        int d = ei[(size_t)E + e];
        int p = rowptr[d] + atomicAdd(&fill[d], 1);
        col[p] = s;
    }
}

// ---------------- conversions ----------------

__global__ void convert_x(const float2* __restrict__ x, uint* __restrict__ xb, int n2) {
    int i = blockIdx.x * 256 + threadIdx.x;
    if (i < n2) {
        float2 v = x[i];
        xb[i] = pack_bf2(v.x, v.y);
    }
}

// W fp32 [k][n] -> Wt bf16 [n][k]
__global__ void convert_w(const float* __restrict__ W, ushort* __restrict__ Wt) {
    int i = blockIdx.x * 256 + threadIdx.x;   // 16384
    int k = i >> 7, nn = i & 127;
    Wt[nn * D + k] = f_to_bf(W[i]);
}

// ---------------- GEMM: Y[n,128] = X[n,128] @ W, bf16 in/out, MFMA ----------
// 256 threads = 4 waves; wave handles 16 rows x 128 cols (8 tiles of 16x16,
// K=128 in 4 steps of 32). A-frags from global X (16B/lane); B-frags from
// global Wt[n][k] (32 KB, L2-resident).
__global__ __launch_bounds__(256)
void gemm_mfma(const ushort* __restrict__ X, const ushort* __restrict__ Wt,
               ushort* __restrict__ Y, int n) {
    int tid = threadIdx.x;
    int wave = tid >> 6, lane = tid & 63;
    int lr = lane & 15, quad = lane >> 4;
    int row0 = blockIdx.x * 64 + wave * 16;
    int ar = min(row0 + lr, n - 1);

    const bf16x8* Arow = (const bf16x8*)(X + (size_t)ar * D);   // 16 chunks of 8

    f32x4 acc[8];
#pragma unroll
    for (int t = 0; t < 8; t++) acc[t] = (f32x4){0.f, 0.f, 0.f, 0.f};

#pragma unroll
    for (int kk = 0; kk < 4; kk++) {
        bf16x8 a = Arow[kk * 4 + quad];   // A[m=lr][k=kk*32+quad*8+j]
#pragma unroll
        for (int nt = 0; nt < 8; nt++) {
            const bf16x8* Brow = (const bf16x8*)(Wt + (size_t)(nt * 16 + lr) * D);
            bf16x8 b = Brow[kk * 4 + quad];   // B[k=kk*32+quad*8+j][n=nt*16+lr]
            acc[nt] = __builtin_amdgcn_mfma_f32_16x16x32_bf16(a, b, acc[nt], 0, 0, 0);
        }
    }

    int crow0 = row0 + quad * 4;          // C: col=lane&15, row=quad*4+reg
#pragma unroll
    for (int nt = 0; nt < 8; nt++) {
#pragma unroll
        for (int r = 0; r < 4; r++) {
            int row = crow0 + r;
            if (row < n) Y[(size_t)row * D + nt * 16 + lr] = f_to_bf(acc[nt][r]);
        }
    }
}

// ---------------- Aggregation ----------------
// out[i] = act( dis[i] * ( sum_{s in N(i)} dis[s]*H[s] + dis[i]*H[i] ) + b )
// H is bf16 [n,128]; one wave per node, uint (bf16x2) per lane.
// MODE 0: relu -> bf16 out. MODE 1: relu + log_softmax -> fp32 out.
template <int MODE>
__global__ __launch_bounds__(256)
void aggregate(const ushort* __restrict__ H, const float* __restrict__ dis,
               const int* __restrict__ rowptr, const int* __restrict__ col,
               const float* __restrict__ bias, void* __restrict__ outv, int n) {
    int node = blockIdx.x * 4 + (threadIdx.x >> 6);
    if (node >= n) return;
    int lane = threadIdx.x & 63;

    float di = dis[node];
    uint u = ((const uint*)(H + (size_t)node * D))[lane];
    float ax = di * bf_lo(u);
    float ay = di * bf_hi(u);

    int beg = rowptr[node], end = rowptr[node + 1];
    for (int j = beg; j < end; j++) {
        int s = col[j];
        float w = dis[s];
        uint v = ((const uint*)(H + (size_t)s * D))[lane];
        ax += w * bf_lo(v);
        ay += w * bf_hi(v);
    }
    float2 b = ((const float2*)bias)[lane];
    ax = fmaxf(di * ax + b.x, 0.f);
    ay = fmaxf(di * ay + b.y, 0.f);

    if (MODE == 1) {
        float m = fmaxf(ax, ay);
        for (int off = 32; off > 0; off >>= 1) m = fmaxf(m, __shfl_xor(m, off));
        float e = __expf(ax - m) + __expf(ay - m);
        for (int off = 32; off > 0; off >>= 1) e += __shfl_xor(e, off);
        float ls = m + __logf(e);
        ((float2*)outv)[(size_t)node * 64 + lane] = make_float2(ax - ls, ay - ls);
    } else {
        ((uint*)outv)[(size_t)node * 64 + lane] = pack_bf2(ax, ay);
    }
}

// ---------------- launcher ----------------

static inline size_t align256(size_t x) { return (x + 255) & ~(size_t)255; }

extern "C" void kernel_launch(void* const* d_in, const int* in_sizes, int n_in,
                              void* d_out, int out_size, void* d_ws, size_t ws_size,
                              hipStream_t stream) {
    const float* x  = (const float*)d_in[0];
    const int*   ei = (const int*)d_in[1];      // int32 (harness-converted)
    const float* W0 = (const float*)d_in[2];
    const float* W1 = (const float*)d_in[3];
    const float* W2 = (const float*)d_in[4];
    const float* b0 = (const float*)d_in[5];
    const float* b1 = (const float*)d_in[6];
    const float* b2 = (const float*)d_in[7];
    float* out      = (float*)d_out;

    const int N = in_sizes[0] / D;
    const int E = in_sizes[1] / 2;

    // workspace (~59 MB)
    char* ws = (char*)d_ws;
    size_t off = 0;
    int*    cnt      = (int*)(ws + off);    off = align256(off + (size_t)N * 4);
    int*    fill     = (int*)(ws + off);    off = align256(off + (size_t)N * 4);
    float*  dis      = (float*)(ws + off);  off = align256(off + (size_t)N * 4);
    int*    rowptr   = (int*)(ws + off);    off = align256(off + ((size_t)N + 1) * 4);
    int*    blocksum = (int*)(ws + off);    off = align256(off + 4096);
    int*    blockoff = (int*)(ws + off);    off = align256(off + 4096);
    ushort* Wt0      = (ushort*)(ws + off); off = align256(off + (size_t)D * D * 2);
    ushort* Wt1      = (ushort*)(ws + off); off = align256(off + (size_t)D * D * 2);
    ushort* Wt2      = (ushort*)(ws + off); off = align256(off + (size_t)D * D * 2);
    int*    col      = (int*)(ws + off);    off = align256(off + (size_t)E * 4);
    ushort* xb       = (ushort*)(ws + off); off = align256(off + (size_t)N * D * 2);
    ushort* gA       = (ushort*)(ws + off); off = align256(off + (size_t)N * D * 2);
    ushort* hb       = (ushort*)d_out;      // first 25.6 MB of d_out; dead before final write
    (void)ws_size;

    const int nbN = (N + 255) / 256;
    const int nbE = (E + 255) / 256;

    // --- CSR build ---
    zero_ints<<<nbN, 256, 0, stream>>>(cnt, N);
    zero_ints<<<nbN, 256, 0, stream>>>(fill, N);
    count_deg<<<nbE, 256, 0, stream>>>(ei, cnt, E);
    compute_dis<<<nbN, 256, 0, stream>>>(cnt, dis, N);
    scan_block<<<nbN, 256, 0, stream>>>(cnt, rowptr, blocksum, N);
    scan_sums<<<1, 512, 0, stream>>>(blocksum, blockoff, nbN);
    add_offsets<<<nbN, 256, 0, stream>>>(rowptr, blockoff, N, E);
    fill_csr<<<nbE, 256, 0, stream>>>(ei, rowptr, fill, col, E);

    // --- conversions ---
    convert_x<<<(N * 64 + 255) / 256, 256, 0, stream>>>((const float2*)x, (uint*)xb, N * 64);
    convert_w<<<64, 256, 0, stream>>>(W0, Wt0);
    convert_w<<<64, 256, 0, stream>>>(W1, Wt1);
    convert_w<<<64, 256, 0, stream>>>(W2, Wt2);

    const int gemmBlocks = (N + 63) / 64;
    const int aggBlocks  = (N + 3) / 4;

    // --- layer 0: xb -> gA -> hb ---
    gemm_mfma<<<gemmBlocks, 256, 0, stream>>>(xb, Wt0, gA, N);
    aggregate<0><<<aggBlocks, 256, 0, stream>>>(gA, dis, rowptr, col, b0, hb, N);
    // --- layer 1: hb -> gA -> xb ---
    gemm_mfma<<<gemmBlocks, 256, 0, stream>>>(hb, Wt1, gA, N);
    aggregate<0><<<aggBlocks, 256, 0, stream>>>(gA, dis, rowptr, col, b1, xb, N);
    // --- layer 2: xb -> gA -> out (fp32, log_softmax) ---
    gemm_mfma<<<gemmBlocks, 256, 0, stream>>>(xb, Wt2, gA, N);
    aggregate<1><<<aggBlocks, 256, 0, stream>>>(gA, dis, rowptr, col, b2, out, N);
}

// Round 5
// 601.054 us; speedup vs baseline: 1.7035x; 1.4195x over previous
//
#include <hip/hip_runtime.h>
#include <cstdint>

// ---------------------------------------------------------------------------
// GCN: 3 x [ h = relu( Ahat (h W) + b ) ], then log_softmax.
// Round 5: (1) GEMM epilogue pre-scales output rows by dis[row], so the
// aggregation edge loop is a pure gather-accumulate (col[j] -> G[s], no dis);
// (2) edge loop unrolled x4 for 4 rows in flight per wave (latency-bound fix);
// (3) GEMM: wave computes 32 rows, B-frags loaded once per K-step and reused
// across 2 row-tiles; layer-0 reads fp32 x directly (no convert_x pass).
// edge_index arrives as int32 (harness converts integer inputs).
// ---------------------------------------------------------------------------

#define D 128

typedef __attribute__((ext_vector_type(8))) short bf16x8;
typedef __attribute__((ext_vector_type(4))) float f32x4;

__device__ inline ushort f_to_bf(float f) {
    uint x = __float_as_uint(f);
    return (ushort)((x + 0x7fffu + ((x >> 16) & 1u)) >> 16);   // RNE
}
__device__ inline uint pack_bf2(float a, float b) {
    return (uint)f_to_bf(a) | ((uint)f_to_bf(b) << 16);
}
__device__ inline float bf_lo(uint u) { return __uint_as_float(u << 16); }
__device__ inline float bf_hi(uint u) { return __uint_as_float(u & 0xffff0000u); }

// ---------------- CSR build ----------------

__global__ void zero_ints(int* __restrict__ a, int n) {
    int i = blockIdx.x * 256 + threadIdx.x;
    if (i < n) a[i] = 0;
}

__global__ void count_deg(const int* __restrict__ ei, int* __restrict__ cnt, int E) {
    int e = blockIdx.x * 256 + threadIdx.x;
    if (e < E) atomicAdd(&cnt[ei[(size_t)E + e]], 1);
}

__global__ void compute_dis(const int* __restrict__ cnt, float* __restrict__ dis, int n) {
    int i = blockIdx.x * 256 + threadIdx.x;
    if (i < n) dis[i] = rsqrtf((float)(cnt[i] + 1));   // self loop -> deg >= 1
}

__global__ void scan_block(const int* __restrict__ cnt, int* __restrict__ rowptr,
                           int* __restrict__ blocksum, int n) {
    __shared__ int s[256];
    int t = threadIdx.x;
    int i = blockIdx.x * 256 + t;
    int v = (i < n) ? cnt[i] : 0;
    s[t] = v;
    __syncthreads();
    for (int off = 1; off < 256; off <<= 1) {
        int u = (t >= off) ? s[t - off] : 0;
        __syncthreads();
        s[t] += u;
        __syncthreads();
    }
    if (i < n) rowptr[i] = s[t] - v;
    if (t == 255) blocksum[blockIdx.x] = s[255];
}

__global__ void scan_sums(const int* __restrict__ blocksum, int* __restrict__ blockoff, int nb) {
    __shared__ int s[512];
    int t = threadIdx.x;
    int carry = 0;
    for (int base = 0; base < nb; base += 512) {
        int idx = base + t;
        int v = (idx < nb) ? blocksum[idx] : 0;
        s[t] = v;
        __syncthreads();
        for (int off = 1; off < 512; off <<= 1) {
            int u = (t >= off) ? s[t - off] : 0;
            __syncthreads();
            s[t] += u;
            __syncthreads();
        }
        if (idx < nb) blockoff[idx] = carry + s[t] - v;
        carry += s[511];
        __syncthreads();
    }
}

__global__ void add_offsets(int* __restrict__ rowptr, const int* __restrict__ blockoff,
                            int n, int E) {
    int i = blockIdx.x * 256 + threadIdx.x;
    if (i < n) rowptr[i] += blockoff[i >> 8];
    if (i == 0) rowptr[n] = E;
}

__global__ void fill_csr(const int* __restrict__ ei, const int* __restrict__ rowptr,
                         int* __restrict__ fill, int* __restrict__ col, int E) {
    int e = blockIdx.x * 256 + threadIdx.x;
    if (e < E) {
        int s = ei[e];
        int d = ei[(size_t)E + e];
        int p = rowptr[d] + atomicAdd(&fill[d], 1);
        col[p] = s;
    }
}

// W fp32 [k][n] -> Wt bf16 [n][k]
__global__ void convert_w(const float* __restrict__ W, ushort* __restrict__ Wt) {
    int i = blockIdx.x * 256 + threadIdx.x;   // 16384
    int k = i >> 7, nn = i & 127;
    Wt[nn * D + k] = f_to_bf(W[i]);
}

// ---------------- GEMM: G[n,128] = dis[row] * (X[n,128] @ W), MFMA ----------
// 256 threads = 4 waves; wave computes 32 rows x 128 cols. Per K-step the 8
// B-frags (transposed W, L1/L2-resident) are loaded once and reused across
// both row-tiles. F32IN: read fp32 X with inline bf16 cvt (layer 0).
template <int F32IN>
__global__ __launch_bounds__(256)
void gemm_mfma(const void* __restrict__ Xv, const ushort* __restrict__ Wt,
               const float* __restrict__ dis, ushort* __restrict__ G, int n) {
    int tid = threadIdx.x;
    int wave = tid >> 6, lane = tid & 63;
    int lr = lane & 15, quad = lane >> 4;
    int rowbase = blockIdx.x * 128 + wave * 32;

    int ar0 = min(rowbase + lr, n - 1);
    int ar1 = min(rowbase + 16 + lr, n - 1);

    f32x4 acc[2][8];
#pragma unroll
    for (int rt = 0; rt < 2; rt++)
#pragma unroll
        for (int nt = 0; nt < 8; nt++) acc[rt][nt] = (f32x4){0.f, 0.f, 0.f, 0.f};

#pragma unroll
    for (int kk = 0; kk < 4; kk++) {
        bf16x8 b[8];
#pragma unroll
        for (int nt = 0; nt < 8; nt++)
            b[nt] = ((const bf16x8*)(Wt + (size_t)(nt * 16 + lr) * D))[kk * 4 + quad];

        bf16x8 a0, a1;
        if (F32IN) {
            const float* X = (const float*)Xv;
            const float* p0 = X + (size_t)ar0 * D + kk * 32 + quad * 8;
            const float* p1 = X + (size_t)ar1 * D + kk * 32 + quad * 8;
            float4 u0 = ((const float4*)p0)[0], v0 = ((const float4*)p0)[1];
            float4 u1 = ((const float4*)p1)[0], v1 = ((const float4*)p1)[1];
            a0 = (bf16x8){(short)f_to_bf(u0.x), (short)f_to_bf(u0.y), (short)f_to_bf(u0.z), (short)f_to_bf(u0.w),
                          (short)f_to_bf(v0.x), (short)f_to_bf(v0.y), (short)f_to_bf(v0.z), (short)f_to_bf(v0.w)};
            a1 = (bf16x8){(short)f_to_bf(u1.x), (short)f_to_bf(u1.y), (short)f_to_bf(u1.z), (short)f_to_bf(u1.w),
                          (short)f_to_bf(v1.x), (short)f_to_bf(v1.y), (short)f_to_bf(v1.z), (short)f_to_bf(v1.w)};
        } else {
            const ushort* X = (const ushort*)Xv;
            a0 = ((const bf16x8*)(X + (size_t)ar0 * D))[kk * 4 + quad];
            a1 = ((const bf16x8*)(X + (size_t)ar1 * D))[kk * 4 + quad];
        }
#pragma unroll
        for (int nt = 0; nt < 8; nt++) {
            acc[0][nt] = __builtin_amdgcn_mfma_f32_16x16x32_bf16(a0, b[nt], acc[0][nt], 0, 0, 0);
            acc[1][nt] = __builtin_amdgcn_mfma_f32_16x16x32_bf16(a1, b[nt], acc[1][nt], 0, 0, 0);
        }
    }

    // epilogue: C col=lane&15, row=quad*4+reg; scale row by dis[row]
#pragma unroll
    for (int rt = 0; rt < 2; rt++) {
#pragma unroll
        for (int r = 0; r < 4; r++) {
            int row = rowbase + rt * 16 + quad * 4 + r;
            if (row < n) {
                float dsc = dis[row];
#pragma unroll
                for (int nt = 0; nt < 8; nt++)
                    G[(size_t)row * D + nt * 16 + lr] = f_to_bf(dsc * acc[rt][nt][r]);
            }
        }
    }
}

// ---------------- Aggregation ----------------
// G rows are pre-scaled by dis[src]. out[i] = act( dis[i]*(sum G[s] + G[i]) + b ).
// One wave per node, uint (bf16x2) per lane; edge loop unrolled x4 for MLP.
// MODE 0: relu -> bf16 out. MODE 1: relu + log_softmax -> fp32 out.
template <int MODE>
__global__ __launch_bounds__(256)
void aggregate(const ushort* __restrict__ Gv, const float* __restrict__ dis,
               const int* __restrict__ rowptr, const int* __restrict__ col,
               const float* __restrict__ bias, void* __restrict__ outv, int n) {
    int node = blockIdx.x * 4 + (threadIdx.x >> 6);
    if (node >= n) return;
    int lane = threadIdx.x & 63;
    const uint* base = (const uint*)Gv;

    uint u = base[(size_t)node * 64 + lane];
    float ax = bf_lo(u), ay = bf_hi(u);

    int beg = rowptr[node], end = rowptr[node + 1];
    int j = beg;
    for (; j + 4 <= end; j += 4) {
        int s0 = col[j], s1 = col[j + 1], s2 = col[j + 2], s3 = col[j + 3];
        uint v0 = base[(size_t)s0 * 64 + lane];
        uint v1 = base[(size_t)s1 * 64 + lane];
        uint v2 = base[(size_t)s2 * 64 + lane];
        uint v3 = base[(size_t)s3 * 64 + lane];
        ax += bf_lo(v0) + bf_lo(v1) + bf_lo(v2) + bf_lo(v3);
        ay += bf_hi(v0) + bf_hi(v1) + bf_hi(v2) + bf_hi(v3);
    }
    for (; j < end; j++) {
        uint v = base[(size_t)col[j] * 64 + lane];
        ax += bf_lo(v);
        ay += bf_hi(v);
    }

    float di = dis[node];
    float2 b = ((const float2*)bias)[lane];
    ax = fmaxf(di * ax + b.x, 0.f);
    ay = fmaxf(di * ay + b.y, 0.f);

    if (MODE == 1) {
        float m = fmaxf(ax, ay);
        for (int off = 32; off > 0; off >>= 1) m = fmaxf(m, __shfl_xor(m, off));
        float e = __expf(ax - m) + __expf(ay - m);
        for (int off = 32; off > 0; off >>= 1) e += __shfl_xor(e, off);
        float ls = m + __logf(e);
        ((float2*)outv)[(size_t)node * 64 + lane] = make_float2(ax - ls, ay - ls);
    } else {
        ((uint*)outv)[(size_t)node * 64 + lane] = pack_bf2(ax, ay);
    }
}

// ---------------- launcher ----------------

static inline size_t align256(size_t x) { return (x + 255) & ~(size_t)255; }

extern "C" void kernel_launch(void* const* d_in, const int* in_sizes, int n_in,
                              void* d_out, int out_size, void* d_ws, size_t ws_size,
                              hipStream_t stream) {
    const float* x  = (const float*)d_in[0];
    const int*   ei = (const int*)d_in[1];      // int32 (harness-converted)
    const float* W0 = (const float*)d_in[2];
    const float* W1 = (const float*)d_in[3];
    const float* W2 = (const float*)d_in[4];
    const float* b0 = (const float*)d_in[5];
    const float* b1 = (const float*)d_in[6];
    const float* b2 = (const float*)d_in[7];
    float* out      = (float*)d_out;

    const int N = in_sizes[0] / D;
    const int E = in_sizes[1] / 2;

    // workspace (~60 MB)
    char* ws = (char*)d_ws;
    size_t off = 0;
    int*    cnt      = (int*)(ws + off);    off = align256(off + (size_t)N * 4);
    int*    fill     = (int*)(ws + off);    off = align256(off + (size_t)N * 4);
    float*  dis      = (float*)(ws + off);  off = align256(off + (size_t)N * 4);
    int*    rowptr   = (int*)(ws + off);    off = align256(off + ((size_t)N + 1) * 4);
    int*    blocksum = (int*)(ws + off);    off = align256(off + 4096);
    int*    blockoff = (int*)(ws + off);    off = align256(off + 4096);
    ushort* Wt0      = (ushort*)(ws + off); off = align256(off + (size_t)D * D * 2);
    ushort* Wt1      = (ushort*)(ws + off); off = align256(off + (size_t)D * D * 2);
    ushort* Wt2      = (ushort*)(ws + off); off = align256(off + (size_t)D * D * 2);
    int*    col      = (int*)(ws + off);    off = align256(off + (size_t)E * 4);
    ushort* xb       = (ushort*)(ws + off); off = align256(off + (size_t)N * D * 2);
    ushort* gA       = (ushort*)(ws + off); off = align256(off + (size_t)N * D * 2);
    ushort* hb       = (ushort*)d_out;      // first 25.6 MB of d_out; dead before final write
    (void)ws_size;

    const int nbN = (N + 255) / 256;
    const int nbE = (E + 255) / 256;

    // --- CSR build ---
    zero_ints<<<nbN, 256, 0, stream>>>(cnt, N);
    zero_ints<<<nbN, 256, 0, stream>>>(fill, N);
    count_deg<<<nbE, 256, 0, stream>>>(ei, cnt, E);
    compute_dis<<<nbN, 256, 0, stream>>>(cnt, dis, N);
    scan_block<<<nbN, 256, 0, stream>>>(cnt, rowptr, blocksum, N);
    scan_sums<<<1, 512, 0, stream>>>(blocksum, blockoff, nbN);
    add_offsets<<<nbN, 256, 0, stream>>>(rowptr, blockoff, N, E);
    fill_csr<<<nbE, 256, 0, stream>>>(ei, rowptr, fill, col, E);

    // --- weight conversions ---
    convert_w<<<64, 256, 0, stream>>>(W0, Wt0);
    convert_w<<<64, 256, 0, stream>>>(W1, Wt1);
    convert_w<<<64, 256, 0, stream>>>(W2, Wt2);

    const int gemmBlocks = (N + 127) / 128;
    const int aggBlocks  = (N + 3) / 4;

    // --- layer 0: x(fp32) -> gA -> hb ---
    gemm_mfma<1><<<gemmBlocks, 256, 0, stream>>>(x, Wt0, dis, gA, N);
    aggregate<0><<<aggBlocks, 256, 0, stream>>>(gA, dis, rowptr, col, b0, hb, N);
    // --- layer 1: hb -> gA -> xb ---
    gemm_mfma<0><<<gemmBlocks, 256, 0, stream>>>(hb, Wt1, dis, gA, N);
    aggregate<0><<<aggBlocks, 256, 0, stream>>>(gA, dis, rowptr, col, b1, xb, N);
    // --- layer 2: xb -> gA -> out (fp32, log_softmax) ---
    gemm_mfma<0><<<gemmBlocks, 256, 0, stream>>>(xb, Wt2, dis, gA, N);
    aggregate<1><<<aggBlocks, 256, 0, stream>>>(gA, dis, rowptr, col, b2, out, N);
}

// Round 6
// 559.021 us; speedup vs baseline: 1.8316x; 1.0752x over previous
//
#include <hip/hip_runtime.h>
#include <cstdint>

// ---------------------------------------------------------------------------
// GCN: 3 x [ h = relu( Ahat (h W) + b ) ], then log_softmax.
// Round 6: CSR build uses blockIdx%8-partitioned count tables (round-robin
// block->XCD dispatch keeps each partition's atomic lines XCD-local, killing
// the cross-XCD ping-pong that made count_deg/fill_csr ~230 us combined).
// Aggregate: half-wave (32 lanes, uint2) per node, edge loop unrolled x4
// -> 8 gather rows in flight per wave. GEMM rows pre-scaled by dis (r5).
// edge_index arrives as int32 (harness converts integer inputs).
// ---------------------------------------------------------------------------

#define D 128
#define NPART 8

typedef __attribute__((ext_vector_type(8))) short bf16x8;
typedef __attribute__((ext_vector_type(4))) float f32x4;

__device__ inline ushort f_to_bf(float f) {
    uint x = __float_as_uint(f);
    return (ushort)((x + 0x7fffu + ((x >> 16) & 1u)) >> 16);   // RNE
}
__device__ inline uint pack_bf2(float a, float b) {
    return (uint)f_to_bf(a) | ((uint)f_to_bf(b) << 16);
}
__device__ inline float bf_lo(uint u) { return __uint_as_float(u << 16); }
__device__ inline float bf_hi(uint u) { return __uint_as_float(u & 0xffff0000u); }

// ---------------- CSR build ----------------

__global__ void zero_ints(int* __restrict__ a, int n) {
    int i = blockIdx.x * 256 + threadIdx.x;
    if (i < n) a[i] = 0;
}

// partitioned degree count: partition = blockIdx & 7 (round-robin ~ XCD-local)
__global__ void count_deg8(const int* __restrict__ ei, int* __restrict__ cnt8,
                           int E, int n) {
    int e = blockIdx.x * 256 + threadIdx.x;
    if (e < E) {
        int p = blockIdx.x & (NPART - 1);
        atomicAdd(&cnt8[(size_t)p * n + ei[(size_t)E + e]], 1);
    }
}

// per node: total degree, per-partition exclusive prefixes (in place), dis
__global__ void node_prep(int* __restrict__ cnt8, int* __restrict__ cnt,
                          float* __restrict__ dis, int n) {
    int i = blockIdx.x * 256 + threadIdx.x;
    if (i >= n) return;
    int s = 0;
#pragma unroll
    for (int p = 0; p < NPART; p++) {
        int t = cnt8[(size_t)p * n + i];
        cnt8[(size_t)p * n + i] = s;
        s += t;
    }
    cnt[i] = s;
    dis[i] = rsqrtf((float)(s + 1));   // self loop -> deg >= 1
}

__global__ void scan_block(const int* __restrict__ cnt, int* __restrict__ rowptr,
                           int* __restrict__ blocksum, int n) {
    __shared__ int s[256];
    int t = threadIdx.x;
    int i = blockIdx.x * 256 + t;
    int v = (i < n) ? cnt[i] : 0;
    s[t] = v;
    __syncthreads();
    for (int off = 1; off < 256; off <<= 1) {
        int u = (t >= off) ? s[t - off] : 0;
        __syncthreads();
        s[t] += u;
        __syncthreads();
    }
    if (i < n) rowptr[i] = s[t] - v;
    if (t == 255) blocksum[blockIdx.x] = s[255];
}

__global__ void scan_sums(const int* __restrict__ blocksum, int* __restrict__ blockoff, int nb) {
    __shared__ int s[512];
    int t = threadIdx.x;
    int carry = 0;
    for (int base = 0; base < nb; base += 512) {
        int idx = base + t;
        int v = (idx < nb) ? blocksum[idx] : 0;
        s[t] = v;
        __syncthreads();
        for (int off = 1; off < 512; off <<= 1) {
            int u = (t >= off) ? s[t - off] : 0;
            __syncthreads();
            s[t] += u;
            __syncthreads();
        }
        if (idx < nb) blockoff[idx] = carry + s[t] - v;
        carry += s[511];
        __syncthreads();
    }
}

__global__ void add_offsets(int* __restrict__ rowptr, const int* __restrict__ blockoff,
                            int n, int E) {
    int i = blockIdx.x * 256 + threadIdx.x;
    if (i < n) rowptr[i] += blockoff[i >> 8];
    if (i == 0) rowptr[n] = E;
}

// fill: slot = rowptr[d] + partition-exclusive-prefix + arrival rank
// (cnt8 holds exclusive prefixes; atomicAdd returns prefix+rank)
__global__ void fill_csr8(const int* __restrict__ ei, const int* __restrict__ rowptr,
                          int* __restrict__ cnt8, int* __restrict__ col, int E, int n) {
    int e = blockIdx.x * 256 + threadIdx.x;
    if (e < E) {
        int p = blockIdx.x & (NPART - 1);
        int s = ei[e];
        int d = ei[(size_t)E + e];
        int slot = rowptr[d] + atomicAdd(&cnt8[(size_t)p * n + d], 1);
        col[slot] = s;
    }
}

// W fp32 [k][n] -> Wt bf16 [n][k]
__global__ void convert_w(const float* __restrict__ W, ushort* __restrict__ Wt) {
    int i = blockIdx.x * 256 + threadIdx.x;   // 16384
    int k = i >> 7, nn = i & 127;
    Wt[nn * D + k] = f_to_bf(W[i]);
}

// ---------------- GEMM: G[n,128] = dis[row] * (X[n,128] @ W), MFMA ----------
// 256 threads = 4 waves; wave computes 32 rows x 128 cols. Per K-step the 8
// B-frags (transposed W, L1/L2-resident) are loaded once and reused across
// both row-tiles. F32IN: read fp32 X with inline bf16 cvt (layer 0).
template <int F32IN>
__global__ __launch_bounds__(256)
void gemm_mfma(const void* __restrict__ Xv, const ushort* __restrict__ Wt,
               const float* __restrict__ dis, ushort* __restrict__ G, int n) {
    int tid = threadIdx.x;
    int wave = tid >> 6, lane = tid & 63;
    int lr = lane & 15, quad = lane >> 4;
    int rowbase = blockIdx.x * 128 + wave * 32;

    int ar0 = min(rowbase + lr, n - 1);
    int ar1 = min(rowbase + 16 + lr, n - 1);

    f32x4 acc[2][8];
#pragma unroll
    for (int rt = 0; rt < 2; rt++)
#pragma unroll
        for (int nt = 0; nt < 8; nt++) acc[rt][nt] = (f32x4){0.f, 0.f, 0.f, 0.f};

#pragma unroll
    for (int kk = 0; kk < 4; kk++) {
        bf16x8 b[8];
#pragma unroll
        for (int nt = 0; nt < 8; nt++)
            b[nt] = ((const bf16x8*)(Wt + (size_t)(nt * 16 + lr) * D))[kk * 4 + quad];

        bf16x8 a0, a1;
        if (F32IN) {
            const float* X = (const float*)Xv;
            const float* p0 = X + (size_t)ar0 * D + kk * 32 + quad * 8;
            const float* p1 = X + (size_t)ar1 * D + kk * 32 + quad * 8;
            float4 u0 = ((const float4*)p0)[0], v0 = ((const float4*)p0)[1];
            float4 u1 = ((const float4*)p1)[0], v1 = ((const float4*)p1)[1];
            a0 = (bf16x8){(short)f_to_bf(u0.x), (short)f_to_bf(u0.y), (short)f_to_bf(u0.z), (short)f_to_bf(u0.w),
                          (short)f_to_bf(v0.x), (short)f_to_bf(v0.y), (short)f_to_bf(v0.z), (short)f_to_bf(v0.w)};
            a1 = (bf16x8){(short)f_to_bf(u1.x), (short)f_to_bf(u1.y), (short)f_to_bf(u1.z), (short)f_to_bf(u1.w),
                          (short)f_to_bf(v1.x), (short)f_to_bf(v1.y), (short)f_to_bf(v1.z), (short)f_to_bf(v1.w)};
        } else {
            const ushort* X = (const ushort*)Xv;
            a0 = ((const bf16x8*)(X + (size_t)ar0 * D))[kk * 4 + quad];
            a1 = ((const bf16x8*)(X + (size_t)ar1 * D))[kk * 4 + quad];
        }
#pragma unroll
        for (int nt = 0; nt < 8; nt++) {
            acc[0][nt] = __builtin_amdgcn_mfma_f32_16x16x32_bf16(a0, b[nt], acc[0][nt], 0, 0, 0);
            acc[1][nt] = __builtin_amdgcn_mfma_f32_16x16x32_bf16(a1, b[nt], acc[1][nt], 0, 0, 0);
        }
    }

    // epilogue: C col=lane&15, row=quad*4+reg; scale row by dis[row]
#pragma unroll
    for (int rt = 0; rt < 2; rt++) {
#pragma unroll
        for (int r = 0; r < 4; r++) {
            int row = rowbase + rt * 16 + quad * 4 + r;
            if (row < n) {
                float dsc = dis[row];
#pragma unroll
                for (int nt = 0; nt < 8; nt++)
                    G[(size_t)row * D + nt * 16 + lr] = f_to_bf(dsc * acc[rt][nt][r]);
            }
        }
    }
}

// ---------------- Aggregation ----------------
// G rows pre-scaled by dis[src]. out[i] = act( dis[i]*(sum G[s] + G[i]) + b ).
// Half-wave (32 lanes, uint2=4 bf16 per lane) per node; edge loop unrolled x4
// -> 8 rows in flight per wave. MODE 0: relu->bf16. MODE 1: +log_softmax->f32.
template <int MODE>
__global__ __launch_bounds__(256)
void aggregate(const ushort* __restrict__ Gv, const float* __restrict__ dis,
               const int* __restrict__ rowptr, const int* __restrict__ col,
               const float* __restrict__ bias, void* __restrict__ outv, int n) {
    int node = blockIdx.x * 8 + (threadIdx.x >> 5);
    if (node >= n) return;
    int lane = threadIdx.x & 31;
    const uint2* base = (const uint2*)Gv;

    uint2 u = base[(size_t)node * 32 + lane];
    float ax = bf_lo(u.x), ay = bf_hi(u.x), az = bf_lo(u.y), aw = bf_hi(u.y);

    int beg = rowptr[node], end = rowptr[node + 1];
    int j = beg;
    for (; j + 4 <= end; j += 4) {
        int s0 = col[j], s1 = col[j + 1], s2 = col[j + 2], s3 = col[j + 3];
        uint2 v0 = base[(size_t)s0 * 32 + lane];
        uint2 v1 = base[(size_t)s1 * 32 + lane];
        uint2 v2 = base[(size_t)s2 * 32 + lane];
        uint2 v3 = base[(size_t)s3 * 32 + lane];
        ax += bf_lo(v0.x) + bf_lo(v1.x) + bf_lo(v2.x) + bf_lo(v3.x);
        ay += bf_hi(v0.x) + bf_hi(v1.x) + bf_hi(v2.x) + bf_hi(v3.x);
        az += bf_lo(v0.y) + bf_lo(v1.y) + bf_lo(v2.y) + bf_lo(v3.y);
        aw += bf_hi(v0.y) + bf_hi(v1.y) + bf_hi(v2.y) + bf_hi(v3.y);
    }
    for (; j < end; j++) {
        uint2 v = base[(size_t)col[j] * 32 + lane];
        ax += bf_lo(v.x); ay += bf_hi(v.x); az += bf_lo(v.y); aw += bf_hi(v.y);
    }

    float di = dis[node];
    float4 b = ((const float4*)bias)[lane];
    ax = fmaxf(di * ax + b.x, 0.f);
    ay = fmaxf(di * ay + b.y, 0.f);
    az = fmaxf(di * az + b.z, 0.f);
    aw = fmaxf(di * aw + b.w, 0.f);

    if (MODE == 1) {
        float m = fmaxf(fmaxf(ax, ay), fmaxf(az, aw));
        for (int off = 16; off > 0; off >>= 1) m = fmaxf(m, __shfl_xor(m, off, 32));
        float e = __expf(ax - m) + __expf(ay - m) + __expf(az - m) + __expf(aw - m);
        for (int off = 16; off > 0; off >>= 1) e += __shfl_xor(e, off, 32);
        float ls = m + __logf(e);
        ((float4*)outv)[(size_t)node * 32 + lane] = make_float4(ax - ls, ay - ls, az - ls, aw - ls);
    } else {
        ((uint2*)outv)[(size_t)node * 32 + lane] = make_uint2(pack_bf2(ax, ay), pack_bf2(az, aw));
    }
}

// ---------------- launcher ----------------

static inline size_t align256(size_t x) { return (x + 255) & ~(size_t)255; }

extern "C" void kernel_launch(void* const* d_in, const int* in_sizes, int n_in,
                              void* d_out, int out_size, void* d_ws, size_t ws_size,
                              hipStream_t stream) {
    const float* x  = (const float*)d_in[0];
    const int*   ei = (const int*)d_in[1];      // int32 (harness-converted)
    const float* W0 = (const float*)d_in[2];
    const float* W1 = (const float*)d_in[3];
    const float* W2 = (const float*)d_in[4];
    const float* b0 = (const float*)d_in[5];
    const float* b1 = (const float*)d_in[6];
    const float* b2 = (const float*)d_in[7];
    float* out      = (float*)d_out;

    const int N = in_sizes[0] / D;
    const int E = in_sizes[1] / 2;

    // workspace (~63 MB)
    char* ws = (char*)d_ws;
    size_t off = 0;
    int*    cnt8     = (int*)(ws + off);    off = align256(off + (size_t)NPART * N * 4);
    int*    cnt      = (int*)(ws + off);    off = align256(off + (size_t)N * 4);
    float*  dis      = (float*)(ws + off);  off = align256(off + (size_t)N * 4);
    int*    rowptr   = (int*)(ws + off);    off = align256(off + ((size_t)N + 1) * 4);
    int*    blocksum = (int*)(ws + off);    off = align256(off + 4096);
    int*    blockoff = (int*)(ws + off);    off = align256(off + 4096);
    ushort* Wt0      = (ushort*)(ws + off); off = align256(off + (size_t)D * D * 2);
    ushort* Wt1      = (ushort*)(ws + off); off = align256(off + (size_t)D * D * 2);
    ushort* Wt2      = (ushort*)(ws + off); off = align256(off + (size_t)D * D * 2);
    int*    col      = (int*)(ws + off);    off = align256(off + (size_t)E * 4);
    ushort* xb       = (ushort*)(ws + off); off = align256(off + (size_t)N * D * 2);
    ushort* gA       = (ushort*)(ws + off); off = align256(off + (size_t)N * D * 2);
    ushort* hb       = (ushort*)d_out;      // first 25.6 MB of d_out; dead before final write
    (void)ws_size;

    const int nbN = (N + 255) / 256;
    const int nbE = (E + 255) / 256;

    // --- CSR build (partitioned atomics) ---
    zero_ints<<<(NPART * N + 255) / 256, 256, 0, stream>>>(cnt8, NPART * N);
    count_deg8<<<nbE, 256, 0, stream>>>(ei, cnt8, E, N);
    node_prep<<<nbN, 256, 0, stream>>>(cnt8, cnt, dis, N);
    scan_block<<<nbN, 256, 0, stream>>>(cnt, rowptr, blocksum, N);
    scan_sums<<<1, 512, 0, stream>>>(blocksum, blockoff, nbN);
    add_offsets<<<nbN, 256, 0, stream>>>(rowptr, blockoff, N, E);
    fill_csr8<<<nbE, 256, 0, stream>>>(ei, rowptr, cnt8, col, E, N);

    // --- weight conversions ---
    convert_w<<<64, 256, 0, stream>>>(W0, Wt0);
    convert_w<<<64, 256, 0, stream>>>(W1, Wt1);
    convert_w<<<64, 256, 0, stream>>>(W2, Wt2);

    const int gemmBlocks = (N + 127) / 128;
    const int aggBlocks  = (N + 7) / 8;

    // --- layer 0: x(fp32) -> gA -> hb ---
    gemm_mfma<1><<<gemmBlocks, 256, 0, stream>>>(x, Wt0, dis, gA, N);
    aggregate<0><<<aggBlocks, 256, 0, stream>>>(gA, dis, rowptr, col, b0, hb, N);
    // --- layer 1: hb -> gA -> xb ---
    gemm_mfma<0><<<gemmBlocks, 256, 0, stream>>>(hb, Wt1, dis, gA, N);
    aggregate<0><<<aggBlocks, 256, 0, stream>>>(gA, dis, rowptr, col, b1, xb, N);
    // --- layer 2: xb -> gA -> out (fp32, log_softmax) ---
    gemm_mfma<0><<<gemmBlocks, 256, 0, stream>>>(xb, Wt2, dis, gA, N);
    aggregate<1><<<aggBlocks, 256, 0, stream>>>(gA, dis, rowptr, col, b2, out, N);
}

// Round 7
// 540.762 us; speedup vs baseline: 1.8934x; 1.0338x over previous
//
#include <hip/hip_runtime.h>
#include <cstdint>

// ---------------------------------------------------------------------------
// GCN: 3 x [ h = relu( Ahat (h W) + b ) ], then log_softmax.
// Round 7: CSR build partitions by DST NODE GROUP: p = (dst>>6)&7, block
// partition = blockIdx&7 (round-robin -> XCD-local). Every col cache line
// (16 slots, one 64-node group) is then written by exactly one XCD -> write
// amplification 104MB -> ~10MB. Each partition scans the full edge stream
// (8x sequential reads, L3 absorbs re-reads). Aggregate: half-wave per node,
// edge loop unrolled x8. GEMM rows pre-scaled by dis (r5).
// edge_index arrives as int32 (harness converts integer inputs).
// ---------------------------------------------------------------------------

#define D 128
#define NPART 8
#define EDGE_CHUNK 16384

typedef __attribute__((ext_vector_type(8))) short bf16x8;
typedef __attribute__((ext_vector_type(4))) float f32x4;

__device__ inline ushort f_to_bf(float f) {
    uint x = __float_as_uint(f);
    return (ushort)((x + 0x7fffu + ((x >> 16) & 1u)) >> 16);   // RNE
}
__device__ inline uint pack_bf2(float a, float b) {
    return (uint)f_to_bf(a) | ((uint)f_to_bf(b) << 16);
}
__device__ inline float bf_lo(uint u) { return __uint_as_float(u << 16); }
__device__ inline float bf_hi(uint u) { return __uint_as_float(u & 0xffff0000u); }

__device__ inline int part_of(int d) { return (d >> 6) & (NPART - 1); }

// ---------------- CSR build ----------------

__global__ void zero_ints(int* __restrict__ a, int n) {
    int i = blockIdx.x * 256 + threadIdx.x;
    if (i < n) a[i] = 0;
}

// partition p scans chunk c of the dst stream; counts only its own nodes.
__global__ void count_deg_part(const int* __restrict__ ei, int* __restrict__ cnt, int E) {
    int p = blockIdx.x & (NPART - 1);
    int c = blockIdx.x >> 3;
    int e0 = c * EDGE_CHUNK;
    int e1 = min(e0 + EDGE_CHUNK, E);
    for (int e = e0 + threadIdx.x; e < e1; e += 256) {
        int d = ei[(size_t)E + e];
        if (part_of(d) == p) atomicAdd(&cnt[d], 1);
    }
}

__global__ void compute_dis(const int* __restrict__ cnt, float* __restrict__ dis, int n) {
    int i = blockIdx.x * 256 + threadIdx.x;
    if (i < n) dis[i] = rsqrtf((float)(cnt[i] + 1));   // self loop -> deg >= 1
}

__global__ void scan_block(const int* __restrict__ cnt, int* __restrict__ rowptr,
                           int* __restrict__ blocksum, int n) {
    __shared__ int s[256];
    int t = threadIdx.x;
    int i = blockIdx.x * 256 + t;
    int v = (i < n) ? cnt[i] : 0;
    s[t] = v;
    __syncthreads();
    for (int off = 1; off < 256; off <<= 1) {
        int u = (t >= off) ? s[t - off] : 0;
        __syncthreads();
        s[t] += u;
        __syncthreads();
    }
    if (i < n) rowptr[i] = s[t] - v;
    if (t == 255) blocksum[blockIdx.x] = s[255];
}

__global__ void scan_sums(const int* __restrict__ blocksum, int* __restrict__ blockoff, int nb) {
    __shared__ int s[512];
    int t = threadIdx.x;
    int carry = 0;
    for (int base = 0; base < nb; base += 512) {
        int idx = base + t;
        int v = (idx < nb) ? blocksum[idx] : 0;
        s[t] = v;
        __syncthreads();
        for (int off = 1; off < 512; off <<= 1) {
            int u = (t >= off) ? s[t - off] : 0;
            __syncthreads();
            s[t] += u;
            __syncthreads();
        }
        if (idx < nb) blockoff[idx] = carry + s[t] - v;
        carry += s[511];
        __syncthreads();
    }
}

__global__ void add_offsets(int* __restrict__ rowptr, const int* __restrict__ blockoff,
                            int n, int E) {
    int i = blockIdx.x * 256 + threadIdx.x;
    if (i < n) rowptr[i] += blockoff[i >> 8];
    if (i == 0) rowptr[n] = E;
}

// partition p scans chunk c; fills col slots only for its own dst nodes.
__global__ void fill_csr_part(const int* __restrict__ ei, const int* __restrict__ rowptr,
                              int* __restrict__ rank, int* __restrict__ col, int E) {
    int p = blockIdx.x & (NPART - 1);
    int c = blockIdx.x >> 3;
    int e0 = c * EDGE_CHUNK;
    int e1 = min(e0 + EDGE_CHUNK, E);
    for (int e = e0 + threadIdx.x; e < e1; e += 256) {
        int d = ei[(size_t)E + e];
        if (part_of(d) == p) {
            int s = ei[e];
            int slot = rowptr[d] + atomicAdd(&rank[d], 1);
            col[slot] = s;
        }
    }
}

// W fp32 [k][n] -> Wt bf16 [n][k]
__global__ void convert_w(const float* __restrict__ W, ushort* __restrict__ Wt) {
    int i = blockIdx.x * 256 + threadIdx.x;   // 16384
    int k = i >> 7, nn = i & 127;
    Wt[nn * D + k] = f_to_bf(W[i]);
}

// ---------------- GEMM: G[n,128] = dis[row] * (X[n,128] @ W), MFMA ----------
// 256 threads = 4 waves; wave computes 32 rows x 128 cols. Per K-step the 8
// B-frags (transposed W, L1/L2-resident) are loaded once and reused across
// both row-tiles. F32IN: read fp32 X with inline bf16 cvt (layer 0).
template <int F32IN>
__global__ __launch_bounds__(256)
void gemm_mfma(const void* __restrict__ Xv, const ushort* __restrict__ Wt,
               const float* __restrict__ dis, ushort* __restrict__ G, int n) {
    int tid = threadIdx.x;
    int wave = tid >> 6, lane = tid & 63;
    int lr = lane & 15, quad = lane >> 4;
    int rowbase = blockIdx.x * 128 + wave * 32;

    int ar0 = min(rowbase + lr, n - 1);
    int ar1 = min(rowbase + 16 + lr, n - 1);

    f32x4 acc[2][8];
#pragma unroll
    for (int rt = 0; rt < 2; rt++)
#pragma unroll
        for (int nt = 0; nt < 8; nt++) acc[rt][nt] = (f32x4){0.f, 0.f, 0.f, 0.f};

#pragma unroll
    for (int kk = 0; kk < 4; kk++) {
        bf16x8 b[8];
#pragma unroll
        for (int nt = 0; nt < 8; nt++)
            b[nt] = ((const bf16x8*)(Wt + (size_t)(nt * 16 + lr) * D))[kk * 4 + quad];

        bf16x8 a0, a1;
        if (F32IN) {
            const float* X = (const float*)Xv;
            const float* p0 = X + (size_t)ar0 * D + kk * 32 + quad * 8;
            const float* p1 = X + (size_t)ar1 * D + kk * 32 + quad * 8;
            float4 u0 = ((const float4*)p0)[0], v0 = ((const float4*)p0)[1];
            float4 u1 = ((const float4*)p1)[0], v1 = ((const float4*)p1)[1];
            a0 = (bf16x8){(short)f_to_bf(u0.x), (short)f_to_bf(u0.y), (short)f_to_bf(u0.z), (short)f_to_bf(u0.w),
                          (short)f_to_bf(v0.x), (short)f_to_bf(v0.y), (short)f_to_bf(v0.z), (short)f_to_bf(v0.w)};
            a1 = (bf16x8){(short)f_to_bf(u1.x), (short)f_to_bf(u1.y), (short)f_to_bf(u1.z), (short)f_to_bf(u1.w),
                          (short)f_to_bf(v1.x), (short)f_to_bf(v1.y), (short)f_to_bf(v1.z), (short)f_to_bf(v1.w)};
        } else {
            const ushort* X = (const ushort*)Xv;
            a0 = ((const bf16x8*)(X + (size_t)ar0 * D))[kk * 4 + quad];
            a1 = ((const bf16x8*)(X + (size_t)ar1 * D))[kk * 4 + quad];
        }
#pragma unroll
        for (int nt = 0; nt < 8; nt++) {
            acc[0][nt] = __builtin_amdgcn_mfma_f32_16x16x32_bf16(a0, b[nt], acc[0][nt], 0, 0, 0);
            acc[1][nt] = __builtin_amdgcn_mfma_f32_16x16x32_bf16(a1, b[nt], acc[1][nt], 0, 0, 0);
        }
    }

    // epilogue: C col=lane&15, row=quad*4+reg; scale row by dis[row]
#pragma unroll
    for (int rt = 0; rt < 2; rt++) {
#pragma unroll
        for (int r = 0; r < 4; r++) {
            int row = rowbase + rt * 16 + quad * 4 + r;
            if (row < n) {
                float dsc = dis[row];
#pragma unroll
                for (int nt = 0; nt < 8; nt++)
                    G[(size_t)row * D + nt * 16 + lr] = f_to_bf(dsc * acc[rt][nt][r]);
            }
        }
    }
}

// ---------------- Aggregation ----------------
// G rows pre-scaled by dis[src]. out[i] = act( dis[i]*(sum G[s] + G[i]) + b ).
// Half-wave (32 lanes, uint2=4 bf16 per lane) per node; edge loop unrolled x8
// -> 16 rows in flight per wave. MODE 0: relu->bf16. MODE 1: +log_softmax->f32.
template <int MODE>
__global__ __launch_bounds__(256)
void aggregate(const ushort* __restrict__ Gv, const float* __restrict__ dis,
               const int* __restrict__ rowptr, const int* __restrict__ col,
               const float* __restrict__ bias, void* __restrict__ outv, int n) {
    int node = blockIdx.x * 8 + (threadIdx.x >> 5);
    if (node >= n) return;
    int lane = threadIdx.x & 31;
    const uint2* base = (const uint2*)Gv;

    uint2 u = base[(size_t)node * 32 + lane];
    float ax = bf_lo(u.x), ay = bf_hi(u.x), az = bf_lo(u.y), aw = bf_hi(u.y);

    int beg = rowptr[node], end = rowptr[node + 1];
    int j = beg;
    for (; j + 8 <= end; j += 8) {
        int s0 = col[j],     s1 = col[j + 1], s2 = col[j + 2], s3 = col[j + 3];
        int s4 = col[j + 4], s5 = col[j + 5], s6 = col[j + 6], s7 = col[j + 7];
        uint2 v0 = base[(size_t)s0 * 32 + lane];
        uint2 v1 = base[(size_t)s1 * 32 + lane];
        uint2 v2 = base[(size_t)s2 * 32 + lane];
        uint2 v3 = base[(size_t)s3 * 32 + lane];
        uint2 v4 = base[(size_t)s4 * 32 + lane];
        uint2 v5 = base[(size_t)s5 * 32 + lane];
        uint2 v6 = base[(size_t)s6 * 32 + lane];
        uint2 v7 = base[(size_t)s7 * 32 + lane];
        ax += bf_lo(v0.x) + bf_lo(v1.x) + bf_lo(v2.x) + bf_lo(v3.x)
            + bf_lo(v4.x) + bf_lo(v5.x) + bf_lo(v6.x) + bf_lo(v7.x);
        ay += bf_hi(v0.x) + bf_hi(v1.x) + bf_hi(v2.x) + bf_hi(v3.x)
            + bf_hi(v4.x) + bf_hi(v5.x) + bf_hi(v6.x) + bf_hi(v7.x);
        az += bf_lo(v0.y) + bf_lo(v1.y) + bf_lo(v2.y) + bf_lo(v3.y)
            + bf_lo(v4.y) + bf_lo(v5.y) + bf_lo(v6.y) + bf_lo(v7.y);
        aw += bf_hi(v0.y) + bf_hi(v1.y) + bf_hi(v2.y) + bf_hi(v3.y)
            + bf_hi(v4.y) + bf_hi(v5.y) + bf_hi(v6.y) + bf_hi(v7.y);
    }
    for (; j < end; j++) {
        uint2 v = base[(size_t)col[j] * 32 + lane];
        ax += bf_lo(v.x); ay += bf_hi(v.x); az += bf_lo(v.y); aw += bf_hi(v.y);
    }

    float di = dis[node];
    float4 b = ((const float4*)bias)[lane];
    ax = fmaxf(di * ax + b.x, 0.f);
    ay = fmaxf(di * ay + b.y, 0.f);
    az = fmaxf(di * az + b.z, 0.f);
    aw = fmaxf(di * aw + b.w, 0.f);

    if (MODE == 1) {
        float m = fmaxf(fmaxf(ax, ay), fmaxf(az, aw));
        for (int off = 16; off > 0; off >>= 1) m = fmaxf(m, __shfl_xor(m, off, 32));
        float e = __expf(ax - m) + __expf(ay - m) + __expf(az - m) + __expf(aw - m);
        for (int off = 16; off > 0; off >>= 1) e += __shfl_xor(e, off, 32);
        float ls = m + __logf(e);
        ((float4*)outv)[(size_t)node * 32 + lane] = make_float4(ax - ls, ay - ls, az - ls, aw - ls);
    } else {
        ((uint2*)outv)[(size_t)node * 32 + lane] = make_uint2(pack_bf2(ax, ay), pack_bf2(az, aw));
    }
}

// ---------------- launcher ----------------

static inline size_t align256(size_t x) { return (x + 255) & ~(size_t)255; }

extern "C" void kernel_launch(void* const* d_in, const int* in_sizes, int n_in,
                              void* d_out, int out_size, void* d_ws, size_t ws_size,
                              hipStream_t stream) {
    const float* x  = (const float*)d_in[0];
    const int*   ei = (const int*)d_in[1];      // int32 (harness-converted)
    const float* W0 = (const float*)d_in[2];
    const float* W1 = (const float*)d_in[3];
    const float* W2 = (const float*)d_in[4];
    const float* b0 = (const float*)d_in[5];
    const float* b1 = (const float*)d_in[6];
    const float* b2 = (const float*)d_in[7];
    float* out      = (float*)d_out;

    const int N = in_sizes[0] / D;
    const int E = in_sizes[1] / 2;

    // workspace (~59 MB)
    char* ws = (char*)d_ws;
    size_t off = 0;
    int*    cnt      = (int*)(ws + off);    off = align256(off + (size_t)N * 4);
    int*    rank     = (int*)(ws + off);    off = align256(off + (size_t)N * 4);
    float*  dis      = (float*)(ws + off);  off = align256(off + (size_t)N * 4);
    int*    rowptr   = (int*)(ws + off);    off = align256(off + ((size_t)N + 1) * 4);
    int*    blocksum = (int*)(ws + off);    off = align256(off + 4096);
    int*    blockoff = (int*)(ws + off);    off = align256(off + 4096);
    ushort* Wt0      = (ushort*)(ws + off); off = align256(off + (size_t)D * D * 2);
    ushort* Wt1      = (ushort*)(ws + off); off = align256(off + (size_t)D * D * 2);
    ushort* Wt2      = (ushort*)(ws + off); off = align256(off + (size_t)D * D * 2);
    int*    col      = (int*)(ws + off);    off = align256(off + (size_t)E * 4);
    ushort* xb       = (ushort*)(ws + off); off = align256(off + (size_t)N * D * 2);
    ushort* gA       = (ushort*)(ws + off); off = align256(off + (size_t)N * D * 2);
    ushort* hb       = (ushort*)d_out;      // first 25.6 MB of d_out; dead before final write
    (void)ws_size;

    const int nbN = (N + 255) / 256;
    const int nchunks = (E + EDGE_CHUNK - 1) / EDGE_CHUNK;
    const int edgeGrid = nchunks * NPART;

    // --- CSR build (dst-group-partitioned atomics & writes) ---
    zero_ints<<<nbN, 256, 0, stream>>>(cnt, N);
    zero_ints<<<nbN, 256, 0, stream>>>(rank, N);
    count_deg_part<<<edgeGrid, 256, 0, stream>>>(ei, cnt, E);
    compute_dis<<<nbN, 256, 0, stream>>>(cnt, dis, N);
    scan_block<<<nbN, 256, 0, stream>>>(cnt, rowptr, blocksum, N);
    scan_sums<<<1, 512, 0, stream>>>(blocksum, blockoff, nbN);
    add_offsets<<<nbN, 256, 0, stream>>>(rowptr, blockoff, N, E);
    fill_csr_part<<<edgeGrid, 256, 0, stream>>>(ei, rowptr, rank, col, E);

    // --- weight conversions ---
    convert_w<<<64, 256, 0, stream>>>(W0, Wt0);
    convert_w<<<64, 256, 0, stream>>>(W1, Wt1);
    convert_w<<<64, 256, 0, stream>>>(W2, Wt2);

    const int gemmBlocks = (N + 127) / 128;
    const int aggBlocks  = (N + 7) / 8;

    // --- layer 0: x(fp32) -> gA -> hb ---
    gemm_mfma<1><<<gemmBlocks, 256, 0, stream>>>(x, Wt0, dis, gA, N);
    aggregate<0><<<aggBlocks, 256, 0, stream>>>(gA, dis, rowptr, col, b0, hb, N);
    // --- layer 1: hb -> gA -> xb ---
    gemm_mfma<0><<<gemmBlocks, 256, 0, stream>>>(hb, Wt1, dis, gA, N);
    aggregate<0><<<aggBlocks, 256, 0, stream>>>(gA, dis, rowptr, col, b1, xb, N);
    // --- layer 2: xb -> gA -> out (fp32, log_softmax) ---
    gemm_mfma<0><<<gemmBlocks, 256, 0, stream>>>(xb, Wt2, dis, gA, N);
    aggregate<1><<<aggBlocks, 256, 0, stream>>>(gA, dis, rowptr, col, b2, out, N);
}